// Round 13
// baseline (305.363 us; speedup 1.0000x reference)
//
#include <hip/hip_runtime.h>

#define N_NODES  100000
#define N_EDGES  3200000
#define N_GRAPHS 1000
#define HDIM     64

#define BUCK_LOG 8
#define BUCK_SZ  256
#define NBUCK    ((N_NODES + BUCK_SZ - 1) / BUCK_SZ)   // 391
#define BIN_T    256
#define BIN_E    16
#define BIN_CHUNK (BIN_T * BIN_E)                      // 4096
#define CLUS_CAP 12288                                 // 48KB LDS adj slice

typedef __attribute__((ext_vector_type(8))) short short8;
typedef __attribute__((ext_vector_type(4))) float f32x4;
typedef __attribute__((ext_vector_type(4))) int   int4v;
typedef __attribute__((ext_vector_type(4))) unsigned uint4v;

// ---------------- bf16 (storage) <-> f32 (math) ----------------

__device__ inline unsigned short f2bf(float v) {
    unsigned int b; __builtin_memcpy(&b, &v, 4);
    return (unsigned short)((b + 0x7FFFu + ((b >> 16) & 1u)) >> 16);   // RNE
}
__device__ inline float bf2f(unsigned short u) {
    return __uint_as_float(((unsigned int)u) << 16);
}
__device__ inline void sth(unsigned short* p, float v) { *p = f2bf(v); }
__device__ inline float bflo(unsigned int d) { return __uint_as_float(d << 16); }
__device__ inline float bfhi(unsigned int d) { return __uint_as_float(d & 0xFFFF0000u); }

__device__ inline int clampi(int v, int lo, int hi) {
    return v < lo ? lo : (v > hi ? hi : v);
}

// ---------------- utility ----------------

__global__ void k_zero(int* __restrict__ p, int n) {
    int i = blockIdx.x * blockDim.x + threadIdx.x;
    if (i < n) p[i] = 0;
}

// ---------------- CSR construction (no per-node global atomics) ----------------

// bucket-level histogram: LDS hist -> one global atomic per (block,bucket)
__global__ __launch_bounds__(BIN_T) void k_bcount(
        const int* __restrict__ ei, int* __restrict__ btot) {
    __shared__ int hist[NBUCK];
    for (int i = threadIdx.x; i < NBUCK; i += BIN_T) hist[i] = 0;
    __syncthreads();
    int e0 = blockIdx.x * BIN_CHUNK + threadIdx.x * BIN_E;
    if (e0 + BIN_E <= N_EDGES) {
        const int4v* d4 = (const int4v*)(ei + N_EDGES);
        #pragma unroll
        for (int q = 0; q < 4; ++q) {
            int4v dv = d4[(e0 >> 2) + q];
            #pragma unroll
            for (int j = 0; j < 4; ++j) {
                int d = clampi(dv[j], 0, N_NODES - 1);
                atomicAdd(&hist[d >> BUCK_LOG], 1);
            }
        }
    } else {
        for (int k = 0; k < BIN_E; ++k) {
            int e = e0 + k;
            if (e < N_EDGES) {
                int d = clampi(ei[N_EDGES + e], 0, N_NODES - 1);
                atomicAdd(&hist[d >> BUCK_LOG], 1);
            }
        }
    }
    __syncthreads();
    for (int i = threadIdx.x; i < NBUCK; i += BIN_T) {
        int c = hist[i];
        if (c) atomicAdd(&btot[i], c);
    }
}

// 391-wide prefix scan -> bucket bases (immutable) + working cursor
__global__ void k_bscan(const int* __restrict__ btot, int* __restrict__ bbase,
                        int* __restrict__ gcur, int* __restrict__ off) {
    __shared__ int s[NBUCK + 1];
    int t = threadIdx.x;
    if (t < NBUCK) s[t] = btot[t];
    __syncthreads();
    if (t == 0) {
        int run = 0;
        for (int i = 0; i < NBUCK; ++i) { int x = s[i]; s[i] = run; run += x; }
        s[NBUCK] = run;                       // == N_EDGES
    }
    __syncthreads();
    if (t <= NBUCK) bbase[t] = s[t];
    if (t < NBUCK)  gcur[t] = s[t];
    if (t == 0)     off[N_NODES] = s[NBUCK];
}

// Pass 1: bin edges by dst bucket; packed 4B pairs ((dlocal<<24)|src).
__global__ __launch_bounds__(BIN_T) void k_bin(
        const int* __restrict__ ei, int* __restrict__ gcur,
        unsigned* __restrict__ pairs) {
    __shared__ int hist[NBUCK];
    __shared__ int base[NBUCK];
    for (int i = threadIdx.x; i < NBUCK; i += BIN_T) hist[i] = 0;
    __syncthreads();
    int e0 = blockIdx.x * BIN_CHUNK + threadIdx.x * BIN_E;
    int d[BIN_E], s[BIN_E];
    if (e0 + BIN_E <= N_EDGES) {
        const int4v* s4 = (const int4v*)ei;
        const int4v* d4 = (const int4v*)(ei + N_EDGES);
        #pragma unroll
        for (int q = 0; q < 4; ++q) {
            int4v dv = d4[(e0 >> 2) + q];
            int4v sv = s4[(e0 >> 2) + q];
            #pragma unroll
            for (int j = 0; j < 4; ++j) {
                d[q * 4 + j] = clampi(dv[j], 0, N_NODES - 1);
                s[q * 4 + j] = clampi(sv[j], 0, N_NODES - 1);
            }
        }
        #pragma unroll
        for (int k = 0; k < BIN_E; ++k) atomicAdd(&hist[d[k] >> BUCK_LOG], 1);
    } else {
        for (int k = 0; k < BIN_E; ++k) {
            int e = e0 + k;
            bool v = e < N_EDGES;
            d[k] = v ? clampi(ei[N_EDGES + e], 0, N_NODES - 1) : -1;
            s[k] = v ? clampi(ei[e], 0, N_NODES - 1) : 0;
            if (v) atomicAdd(&hist[d[k] >> BUCK_LOG], 1);
        }
    }
    __syncthreads();
    for (int i = threadIdx.x; i < NBUCK; i += BIN_T) {
        int c = hist[i];
        base[i] = c ? atomicAdd(&gcur[i], c) : 0;
        hist[i] = 0;                         // reuse as local rank
    }
    __syncthreads();
    #pragma unroll
    for (int k = 0; k < BIN_E; ++k) {
        if (d[k] >= 0) {
            int b = d[k] >> BUCK_LOG;
            int r = atomicAdd(&hist[b], 1);
            pairs[base[b] + r] = ((unsigned)(d[k] & (BUCK_SZ - 1)) << 24) | (unsigned)s[k];
        }
    }
}

// Pass 2: one block per bucket. LDS degree hist + scan -> off (coalesced),
// LDS scatter -> adj (coalesced stream-out).
__global__ __launch_bounds__(512) void k_cluster(
        const unsigned* __restrict__ pairs, const int* __restrict__ bbase,
        int* __restrict__ off, int* __restrict__ adj) {
    __shared__ int ladj[CLUS_CAP];
    __shared__ int lcur[BUCK_SZ];            // deg -> cursor
    __shared__ int lsc[BUCK_SZ];             // scan workspace
    int b  = blockIdx.x;
    int lo = b * BUCK_SZ;
    int nn = N_NODES - lo; if (nn > BUCK_SZ) nn = BUCK_SZ;
    int e0 = bbase[b], e1 = bbase[b + 1];
    int cnt = e1 - e0;
    if (threadIdx.x < BUCK_SZ) lcur[threadIdx.x] = 0;
    __syncthreads();
    for (int i = threadIdx.x; i < cnt; i += 512) {
        unsigned p = pairs[e0 + i];
        atomicAdd(&lcur[p >> 24], 1);
    }
    __syncthreads();
    int v = 0;
    if (threadIdx.x < BUCK_SZ) { v = lcur[threadIdx.x]; lsc[threadIdx.x] = v; }
    __syncthreads();
    #pragma unroll
    for (int d = 1; d < BUCK_SZ; d <<= 1) {
        int add = 0;
        if (threadIdx.x < BUCK_SZ && threadIdx.x >= d) add = lsc[threadIdx.x - d];
        __syncthreads();
        if (threadIdx.x < BUCK_SZ) lsc[threadIdx.x] += add;
        __syncthreads();
    }
    if (threadIdx.x < BUCK_SZ) {
        int exc = lsc[threadIdx.x] - v;
        if (threadIdx.x < nn) off[lo + threadIdx.x] = e0 + exc;
        lcur[threadIdx.x] = exc;
    }
    __syncthreads();
    if (cnt <= CLUS_CAP) {
        for (int i = threadIdx.x; i < cnt; i += 512) {
            unsigned p = pairs[e0 + i];
            int pos = atomicAdd(&lcur[p >> 24], 1);
            ladj[pos] = (int)(p & 0xFFFFFFu);
        }
        __syncthreads();
        for (int i = threadIdx.x; i < cnt; i += 512) adj[e0 + i] = ladj[i];
    } else {                                  // safety fallback (never expected)
        for (int i = threadIdx.x; i < cnt; i += 512) {
            unsigned p = pairs[e0 + i];
            int pos = atomicAdd(&lcur[p >> 24], 1);
            adj[e0 + pos] = (int)(p & 0xFFFFFFu);
        }
    }
}

// ---------------- Layer 1 (F_IN = 3): fused agg + 3x64 matmul ----------------

__global__ __launch_bounds__(256) void k_layer1(
        const float* __restrict__ x, const int* __restrict__ off,
        const int* __restrict__ adj, const float* __restrict__ epsp,
        const float* __restrict__ W1, const float* __restrict__ b1,
        unsigned short* __restrict__ hout) {
    int wid  = (blockIdx.x * blockDim.x + threadIdx.x) >> 6;   // node
    int lane = threadIdx.x & 63;
    if (wid >= N_NODES) return;
    int o0 = off[wid], o1 = off[wid + 1];
    float a0 = 0.f, a1 = 0.f, a2 = 0.f;
    for (int e = o0 + lane; e < o1; e += 64) {
        int s = adj[e];
        a0 += x[s * 3 + 0];
        a1 += x[s * 3 + 1];
        a2 += x[s * 3 + 2];
    }
    #pragma unroll
    for (int d = 32; d; d >>= 1) {
        a0 += __shfl_xor(a0, d);
        a1 += __shfl_xor(a1, d);
        a2 += __shfl_xor(a2, d);
    }
    float ep = 1.0f + epsp[0];
    float s0 = ep * x[wid * 3 + 0] + a0;
    float s1 = ep * x[wid * 3 + 1] + a1;
    float s2 = ep * x[wid * 3 + 2] + a2;
    float o = b1[lane] + s0 * W1[lane] + s1 * W1[64 + lane] + s2 * W1[128 + lane];
    sth(&hout[(size_t)wid * 64 + lane], fmaxf(o, 0.f));
}

// ---------------- Dense GEMM: Y = h @ W  (100000x64 @ 64x64, bf16 MFMA) -------

__global__ __launch_bounds__(256) void k_gemm(
        const unsigned short* __restrict__ hin, const float* __restrict__ W,
        unsigned short* __restrict__ Y) {
    int lane = threadIdx.x & 63;
    int r = lane & 15;
    int g = lane >> 4;
    int wave   = blockIdx.x * (blockDim.x >> 6) + (threadIdx.x >> 6);
    int nwaves = gridDim.x * (blockDim.x >> 6);

    short8 bh[2][4], bl[2][4];
    #pragma unroll
    for (int s = 0; s < 2; ++s) {
        #pragma unroll
        for (int t = 0; t < 4; ++t) {
            short8 hv, lv;
            #pragma unroll
            for (int i = 0; i < 8; ++i) {
                int k = s * 32 + g * 8 + i;
                int n = t * 16 + r;
                float w = W[k * 64 + n];
                unsigned short wh = f2bf(w);
                float whf = bf2f(wh);
                hv[i] = (short)wh;
                lv[i] = (short)f2bf(w - whf);
            }
            bh[s][t] = hv; bl[s][t] = lv;
        }
    }

    const int NT = N_NODES / 16;   // 6250 (exact)
    for (int mt = wave; mt < NT; mt += nwaves) {
        const unsigned short* arow = hin + (size_t)(mt * 16 + r) * 64;
        short8 a0 = *(const short8*)(arow + g * 8);
        short8 a1 = *(const short8*)(arow + 32 + g * 8);
        #pragma unroll
        for (int t = 0; t < 4; ++t) {
            f32x4 acc = {0.f, 0.f, 0.f, 0.f};
            acc = __builtin_amdgcn_mfma_f32_16x16x32_bf16(a0, bh[0][t], acc, 0, 0, 0);
            acc = __builtin_amdgcn_mfma_f32_16x16x32_bf16(a0, bl[0][t], acc, 0, 0, 0);
            acc = __builtin_amdgcn_mfma_f32_16x16x32_bf16(a1, bh[1][t], acc, 0, 0, 0);
            acc = __builtin_amdgcn_mfma_f32_16x16x32_bf16(a1, bl[1][t], acc, 0, 0, 0);
            #pragma unroll
            for (int j = 0; j < 4; ++j) {
                sth(&Y[(size_t)(mt * 16 + g * 4 + j) * 64 + t * 16 + r], acc[j]);
            }
        }
    }
}

// ---------------- Gather: out = relu(b + (1+eps)*Y_self + sum_nbr Y_nbr) ------
// 8 lanes per node (8 nodes/wave). Lane sl holds feature octet 8sl..8sl+7
// (one uint4 = 16B). Each load instruction fetches 8 full neighbor rows.

__device__ inline void gather8(
        const uint4v* __restrict__ h4, const int* __restrict__ off,
        const int* __restrict__ adj, int node, int sl, int g8, float acc[8]) {
    int o0 = off[node], o1 = off[node + 1];
    int deg = o1 - o0;
    for (int base = 0; base < deg; base += 8) {
        int pos = o0 + base + sl;
        int posc = pos < o1 ? pos : (o1 - 1);
        int idxv = adj[posc];
        int rem = deg - base;
        uint4v dd[8];
        #pragma unroll
        for (int k = 0; k < 8; ++k) {
            int s = __shfl(idxv, (g8 << 3) + k);
            dd[k] = h4[(size_t)s * 8 + sl];
        }
        #pragma unroll
        for (int k = 0; k < 8; ++k) {
            bool ok = k < rem;
            unsigned x0 = ok ? dd[k][0] : 0u;
            unsigned x1 = ok ? dd[k][1] : 0u;
            unsigned x2 = ok ? dd[k][2] : 0u;
            unsigned x3 = ok ? dd[k][3] : 0u;
            acc[0] += bflo(x0); acc[1] += bfhi(x0);
            acc[2] += bflo(x1); acc[3] += bfhi(x1);
            acc[4] += bflo(x2); acc[5] += bfhi(x2);
            acc[6] += bflo(x3); acc[7] += bfhi(x3);
        }
    }
}

__global__ __launch_bounds__(1024) void k_gather(
        const unsigned short* __restrict__ Y, const int* __restrict__ off,
        const int* __restrict__ adj, const float* __restrict__ epsp,
        const float* __restrict__ b, unsigned short* __restrict__ hout) {
    int tid  = blockIdx.x * 1024 + threadIdx.x;
    int node = tid >> 3;
    if (node >= N_NODES) return;
    int sl = threadIdx.x & 7;
    int g8 = (threadIdx.x >> 3) & 7;
    const uint4v* h4 = (const uint4v*)Y;
    float acc[8] = {0.f, 0.f, 0.f, 0.f, 0.f, 0.f, 0.f, 0.f};
    gather8(h4, off, adj, node, sl, g8, acc);
    uint4v ds = h4[(size_t)node * 8 + sl];
    float ep = 1.0f + epsp[0];
    acc[0] += ep * bflo(ds[0]); acc[1] += ep * bfhi(ds[0]);
    acc[2] += ep * bflo(ds[1]); acc[3] += ep * bfhi(ds[1]);
    acc[4] += ep * bflo(ds[2]); acc[5] += ep * bfhi(ds[2]);
    acc[6] += ep * bflo(ds[3]); acc[7] += ep * bfhi(ds[3]);
    uint4v o;
    #pragma unroll
    for (int i = 0; i < 4; ++i) {
        float lo = fmaxf(acc[2 * i]     + b[8 * sl + 2 * i],     0.f);
        float hi = fmaxf(acc[2 * i + 1] + b[8 * sl + 2 * i + 1], 0.f);
        o[i] = (unsigned)f2bf(lo) | ((unsigned)f2bf(hi) << 16);
    }
    ((uint4v*)hout)[(size_t)node * 8 + sl] = o;
}

__global__ __launch_bounds__(1024) void k_gather_pool(
        const unsigned short* __restrict__ Y, const int* __restrict__ off,
        const int* __restrict__ adj, const float* __restrict__ epsp,
        const float* __restrict__ b, const int* __restrict__ batch,
        float* __restrict__ pooled, int* __restrict__ cnt) {
    __shared__ float sacc[8 * 64];
    __shared__ int   scnt[8];
    for (int i = threadIdx.x; i < 8 * 64; i += 1024) sacc[i] = 0.f;
    if (threadIdx.x < 8) scnt[threadIdx.x] = 0;
    __syncthreads();

    int tid  = blockIdx.x * 1024 + threadIdx.x;
    int node = tid >> 3;
    int sl = threadIdx.x & 7;
    int g8 = (threadIdx.x >> 3) & 7;
    int g0 = clampi(batch[clampi(blockIdx.x << 7, 0, N_NODES - 1)], 0, N_GRAPHS - 1);

    if (node < N_NODES) {
        const uint4v* h4 = (const uint4v*)Y;
        float acc[8] = {0.f, 0.f, 0.f, 0.f, 0.f, 0.f, 0.f, 0.f};
        gather8(h4, off, adj, node, sl, g8, acc);
        uint4v ds = h4[(size_t)node * 8 + sl];
        float ep = 1.0f + epsp[0];
        acc[0] += ep * bflo(ds[0]); acc[1] += ep * bfhi(ds[0]);
        acc[2] += ep * bflo(ds[1]); acc[3] += ep * bfhi(ds[1]);
        acc[4] += ep * bflo(ds[2]); acc[5] += ep * bfhi(ds[2]);
        acc[6] += ep * bflo(ds[3]); acc[7] += ep * bfhi(ds[3]);
        int g  = clampi(batch[node], 0, N_GRAPHS - 1);
        int og = g - g0;
        if (og >= 0 && og < 8) {
            #pragma unroll
            for (int i = 0; i < 8; ++i)
                atomicAdd(&sacc[og * 64 + 8 * sl + i], fmaxf(acc[i] + b[8 * sl + i], 0.f));
            if (sl == 0) atomicAdd(&scnt[og], 1);
        } else {
            #pragma unroll
            for (int i = 0; i < 8; ++i)
                atomicAdd(&pooled[g * 64 + 8 * sl + i], fmaxf(acc[i] + b[8 * sl + i], 0.f));
            if (sl == 0) atomicAdd(&cnt[g], 1);
        }
    }
    __syncthreads();
    int w = threadIdx.x >> 6;                // waves 0..7 flush slots
    int lane = threadIdx.x & 63;
    if (w < 8) {
        int c = scnt[w];
        if (c > 0) {
            atomicAdd(&pooled[(g0 + w) * 64 + lane], sacc[w * 64 + lane]);
            if (lane == 0) atomicAdd(&cnt[g0 + w], c);
        }
    }
}

// ---------------- Head: mean, 64->10 relu, 10->1 ----------------

__global__ __launch_bounds__(256) void k_head(
        const float* __restrict__ pooled, const int* __restrict__ cnt,
        const float* __restrict__ Wf1, const float* __restrict__ bf1,
        const float* __restrict__ Wf2, const float* __restrict__ bf2,
        float* __restrict__ out) {
    int g = blockIdx.x * blockDim.x + threadIdx.x;
    if (g >= N_GRAPHS) return;
    float inv = 1.0f / fmaxf((float)cnt[g], 1.0f);
    float p[64];
    #pragma unroll
    for (int k = 0; k < 64; ++k) p[k] = pooled[g * 64 + k] * inv;
    float o = bf2[0];
    #pragma unroll
    for (int j = 0; j < 10; ++j) {
        float s = bf1[j];
        #pragma unroll
        for (int k = 0; k < 64; ++k) s += p[k] * Wf1[k * 10 + j];
        o += fmaxf(s, 0.f) * Wf2[j];
    }
    out[g] = o;
}

// ---------------- launch ----------------

extern "C" void kernel_launch(void* const* d_in, const int* in_sizes, int n_in,
                              void* d_out, int out_size, void* d_ws, size_t ws_size,
                              hipStream_t stream) {
    const float* x     = (const float*)d_in[0];
    const int*   ei    = (const int*)d_in[1];    // int64 in ref -> int32 on device
    const int*   batch = (const int*)d_in[2];
    const float* eps1 = (const float*)d_in[3];
    const float* eps2 = (const float*)d_in[4];
    const float* eps3 = (const float*)d_in[5];
    const float* W1 = (const float*)d_in[6];
    const float* b1 = (const float*)d_in[7];
    const float* W2 = (const float*)d_in[8];
    const float* b2 = (const float*)d_in[9];
    const float* W3 = (const float*)d_in[10];
    const float* b3 = (const float*)d_in[11];
    const float* Wf1 = (const float*)d_in[12];
    const float* bf1 = (const float*)d_in[13];
    const float* Wf2 = (const float*)d_in[14];
    const float* bf2 = (const float*)d_in[15];
    float* out = (float*)d_out;

    const size_t H64 = (size_t)N_NODES * HDIM;          // 6,400,000 elems

    char* base = (char*)d_ws;
    unsigned short* hA = (unsigned short*)base;                    // 12.8 MB
    unsigned short* hB = (unsigned short*)(base + H64 * 2);        // 12.8 MB
    unsigned* pairs = (unsigned*)base;   // 12.8 MB, aliases hA (CSR build only)
    char* q = base + 2 * H64 * 2;
    float* pooled = (float*)q;            q += 64000ull * 4;
    int*   cnt    = (int*)q;              q += 1000ull * 4;
    int*   off    = (int*)q;              q += 100004ull * 4;
    int*   btot   = (int*)q;              q += 512ull * 4;
    int*   bbase  = (int*)q;              q += 512ull * 4;
    int*   gcur   = (int*)q;              q += 512ull * 4;
    int*   adj    = (int*)q;

    const int TB = 256;
    k_zero<<<(65000 + TB - 1) / TB, TB, 0, stream>>>((int*)pooled, 65000);
    k_zero<<<2, TB, 0, stream>>>(btot, NBUCK);

    // CSR build: bucket count -> bucket scan -> bin (packed pairs) -> cluster
    const int BINB = (N_EDGES + BIN_CHUNK - 1) / BIN_CHUNK;   // 782
    k_bcount<<<BINB, BIN_T, 0, stream>>>(ei, btot);
    k_bscan<<<1, 512, 0, stream>>>(btot, bbase, gcur, off);
    k_bin<<<BINB, BIN_T, 0, stream>>>(ei, gcur, pairs);
    k_cluster<<<NBUCK, 512, 0, stream>>>(pairs, bbase, off, adj);

    const int L1_BLOCKS = (int)((H64 + TB - 1) / TB);        // 4 nodes/block @256
    const int GB = (N_NODES * 8 + 1023) / 1024;              // 782 (128 nodes/blk)

    // layer 1 (fused, cheap gathers of 12B x-rows; x is L2-resident)
    k_layer1<<<L1_BLOCKS, TB, 0, stream>>>(x, off, adj, eps1, W1, b1, hA);
    // layer 2: GEMM then gather
    k_gemm<<<256, 256, 0, stream>>>(hA, W2, hB);
    k_gather<<<GB, 1024, 0, stream>>>(hB, off, adj, eps2, b2, hA);
    // layer 3: GEMM then gather+pool
    k_gemm<<<256, 256, 0, stream>>>(hA, W3, hB);
    k_gather_pool<<<GB, 1024, 0, stream>>>(hB, off, adj, eps3, b3, batch, pooled, cnt);

    k_head<<<(N_GRAPHS + TB - 1) / TB, TB, 0, stream>>>(pooled, cnt, Wf1, bf1, Wf2, bf2, out);
}

// Round 14
// 266.510 us; speedup vs baseline: 1.1458x; 1.1458x over previous
//
#include <hip/hip_runtime.h>

#define N_NODES  100000
#define N_EDGES  3200000
#define N_GRAPHS 1000
#define HDIM     64

#define BUCK_LOG 8
#define BUCK_SZ  256
#define NBUCK    ((N_NODES + BUCK_SZ - 1) / BUCK_SZ)   // 391
#define BIN_T    256
#define BIN_E    16
#define BIN_CHUNK (BIN_T * BIN_E)                      // 4096
#define CLUS_CAP 12288                                 // 48KB LDS adj slice

typedef __attribute__((ext_vector_type(8))) short short8;
typedef __attribute__((ext_vector_type(4))) float f32x4;
typedef __attribute__((ext_vector_type(4))) int   int4v;

// ---------------- bf16 (storage) <-> f32 (math) ----------------

__device__ inline unsigned short f2bf(float v) {
    unsigned int b; __builtin_memcpy(&b, &v, 4);
    return (unsigned short)((b + 0x7FFFu + ((b >> 16) & 1u)) >> 16);   // RNE
}
__device__ inline float bf2f(unsigned short u) {
    return __uint_as_float(((unsigned int)u) << 16);
}
__device__ inline void sth(unsigned short* p, float v) { *p = f2bf(v); }
__device__ inline float bflo(unsigned int d) { return __uint_as_float(d << 16); }
__device__ inline float bfhi(unsigned int d) { return __uint_as_float(d & 0xFFFF0000u); }

__device__ inline int clampi(int v, int lo, int hi) {
    return v < lo ? lo : (v > hi ? hi : v);
}

// ---------------- utility ----------------

__global__ void k_zero(int* __restrict__ p, int n) {
    int i = blockIdx.x * blockDim.x + threadIdx.x;
    if (i < n) p[i] = 0;
}

// ---------------- CSR construction (no per-node global atomics) ----------------

__global__ __launch_bounds__(BIN_T) void k_bcount(
        const int* __restrict__ ei, int* __restrict__ btot) {
    __shared__ int hist[NBUCK];
    for (int i = threadIdx.x; i < NBUCK; i += BIN_T) hist[i] = 0;
    __syncthreads();
    int e0 = blockIdx.x * BIN_CHUNK + threadIdx.x * BIN_E;
    if (e0 + BIN_E <= N_EDGES) {
        const int4v* d4 = (const int4v*)(ei + N_EDGES);
        #pragma unroll
        for (int q = 0; q < 4; ++q) {
            int4v dv = d4[(e0 >> 2) + q];
            #pragma unroll
            for (int j = 0; j < 4; ++j) {
                int d = clampi(dv[j], 0, N_NODES - 1);
                atomicAdd(&hist[d >> BUCK_LOG], 1);
            }
        }
    } else {
        for (int k = 0; k < BIN_E; ++k) {
            int e = e0 + k;
            if (e < N_EDGES) {
                int d = clampi(ei[N_EDGES + e], 0, N_NODES - 1);
                atomicAdd(&hist[d >> BUCK_LOG], 1);
            }
        }
    }
    __syncthreads();
    for (int i = threadIdx.x; i < NBUCK; i += BIN_T) {
        int c = hist[i];
        if (c) atomicAdd(&btot[i], c);
    }
}

__global__ void k_bscan(const int* __restrict__ btot, int* __restrict__ bbase,
                        int* __restrict__ gcur, int* __restrict__ off) {
    __shared__ int s[NBUCK + 1];
    int t = threadIdx.x;
    if (t < NBUCK) s[t] = btot[t];
    __syncthreads();
    if (t == 0) {
        int run = 0;
        for (int i = 0; i < NBUCK; ++i) { int x = s[i]; s[i] = run; run += x; }
        s[NBUCK] = run;                       // == N_EDGES
    }
    __syncthreads();
    if (t <= NBUCK) bbase[t] = s[t];
    if (t < NBUCK)  gcur[t] = s[t];
    if (t == 0)     off[N_NODES] = s[NBUCK];
}

// Pass 1: bin edges by dst bucket; packed 4B pairs ((dlocal<<24)|src).
__global__ __launch_bounds__(BIN_T) void k_bin(
        const int* __restrict__ ei, int* __restrict__ gcur,
        unsigned* __restrict__ pairs) {
    __shared__ int hist[NBUCK];
    __shared__ int base[NBUCK];
    for (int i = threadIdx.x; i < NBUCK; i += BIN_T) hist[i] = 0;
    __syncthreads();
    int e0 = blockIdx.x * BIN_CHUNK + threadIdx.x * BIN_E;
    int d[BIN_E], s[BIN_E];
    if (e0 + BIN_E <= N_EDGES) {
        const int4v* s4 = (const int4v*)ei;
        const int4v* d4 = (const int4v*)(ei + N_EDGES);
        #pragma unroll
        for (int q = 0; q < 4; ++q) {
            int4v dv = d4[(e0 >> 2) + q];
            int4v sv = s4[(e0 >> 2) + q];
            #pragma unroll
            for (int j = 0; j < 4; ++j) {
                d[q * 4 + j] = clampi(dv[j], 0, N_NODES - 1);
                s[q * 4 + j] = clampi(sv[j], 0, N_NODES - 1);
            }
        }
        #pragma unroll
        for (int k = 0; k < BIN_E; ++k) atomicAdd(&hist[d[k] >> BUCK_LOG], 1);
    } else {
        for (int k = 0; k < BIN_E; ++k) {
            int e = e0 + k;
            bool v = e < N_EDGES;
            d[k] = v ? clampi(ei[N_EDGES + e], 0, N_NODES - 1) : -1;
            s[k] = v ? clampi(ei[e], 0, N_NODES - 1) : 0;
            if (v) atomicAdd(&hist[d[k] >> BUCK_LOG], 1);
        }
    }
    __syncthreads();
    for (int i = threadIdx.x; i < NBUCK; i += BIN_T) {
        int c = hist[i];
        base[i] = c ? atomicAdd(&gcur[i], c) : 0;
        hist[i] = 0;                         // reuse as local rank
    }
    __syncthreads();
    #pragma unroll
    for (int k = 0; k < BIN_E; ++k) {
        if (d[k] >= 0) {
            int b = d[k] >> BUCK_LOG;
            int r = atomicAdd(&hist[b], 1);
            pairs[base[b] + r] = ((unsigned)(d[k] & (BUCK_SZ - 1)) << 24) | (unsigned)s[k];
        }
    }
}

// Pass 2: one block per bucket. LDS degree hist + scan -> off (coalesced),
// LDS scatter -> adj (coalesced stream-out).
__global__ __launch_bounds__(512) void k_cluster(
        const unsigned* __restrict__ pairs, const int* __restrict__ bbase,
        int* __restrict__ off, int* __restrict__ adj) {
    __shared__ int ladj[CLUS_CAP];
    __shared__ int lcur[BUCK_SZ];            // deg -> cursor
    __shared__ int lsc[BUCK_SZ];             // scan workspace
    int b  = blockIdx.x;
    int lo = b * BUCK_SZ;
    int nn = N_NODES - lo; if (nn > BUCK_SZ) nn = BUCK_SZ;
    int e0 = bbase[b], e1 = bbase[b + 1];
    int cnt = e1 - e0;
    if (threadIdx.x < BUCK_SZ) lcur[threadIdx.x] = 0;
    __syncthreads();
    for (int i = threadIdx.x; i < cnt; i += 512) {
        unsigned p = pairs[e0 + i];
        atomicAdd(&lcur[p >> 24], 1);
    }
    __syncthreads();
    int v = 0;
    if (threadIdx.x < BUCK_SZ) { v = lcur[threadIdx.x]; lsc[threadIdx.x] = v; }
    __syncthreads();
    #pragma unroll
    for (int d = 1; d < BUCK_SZ; d <<= 1) {
        int add = 0;
        if (threadIdx.x < BUCK_SZ && threadIdx.x >= d) add = lsc[threadIdx.x - d];
        __syncthreads();
        if (threadIdx.x < BUCK_SZ) lsc[threadIdx.x] += add;
        __syncthreads();
    }
    if (threadIdx.x < BUCK_SZ) {
        int exc = lsc[threadIdx.x] - v;
        if (threadIdx.x < nn) off[lo + threadIdx.x] = e0 + exc;
        lcur[threadIdx.x] = exc;
    }
    __syncthreads();
    if (cnt <= CLUS_CAP) {
        for (int i = threadIdx.x; i < cnt; i += 512) {
            unsigned p = pairs[e0 + i];
            int pos = atomicAdd(&lcur[p >> 24], 1);
            ladj[pos] = (int)(p & 0xFFFFFFu);
        }
        __syncthreads();
        for (int i = threadIdx.x; i < cnt; i += 512) adj[e0 + i] = ladj[i];
    } else {                                  // safety fallback (never expected)
        for (int i = threadIdx.x; i < cnt; i += 512) {
            unsigned p = pairs[e0 + i];
            int pos = atomicAdd(&lcur[p >> 24], 1);
            adj[e0 + pos] = (int)(p & 0xFFFFFFu);
        }
    }
}

// ---------------- Layer 1 (F_IN = 3): fused agg + 3x64 matmul ----------------

__global__ __launch_bounds__(256) void k_layer1(
        const float* __restrict__ x, const int* __restrict__ off,
        const int* __restrict__ adj, const float* __restrict__ epsp,
        const float* __restrict__ W1, const float* __restrict__ b1,
        unsigned short* __restrict__ hout) {
    int wid  = (blockIdx.x * blockDim.x + threadIdx.x) >> 6;   // node
    int lane = threadIdx.x & 63;
    if (wid >= N_NODES) return;
    int o0 = off[wid], o1 = off[wid + 1];
    float a0 = 0.f, a1 = 0.f, a2 = 0.f;
    for (int e = o0 + lane; e < o1; e += 64) {
        int s = adj[e];
        a0 += x[s * 3 + 0];
        a1 += x[s * 3 + 1];
        a2 += x[s * 3 + 2];
    }
    #pragma unroll
    for (int d = 32; d; d >>= 1) {
        a0 += __shfl_xor(a0, d);
        a1 += __shfl_xor(a1, d);
        a2 += __shfl_xor(a2, d);
    }
    float ep = 1.0f + epsp[0];
    float s0 = ep * x[wid * 3 + 0] + a0;
    float s1 = ep * x[wid * 3 + 1] + a1;
    float s2 = ep * x[wid * 3 + 2] + a2;
    float o = b1[lane] + s0 * W1[lane] + s1 * W1[64 + lane] + s2 * W1[128 + lane];
    sth(&hout[(size_t)wid * 64 + lane], fmaxf(o, 0.f));
}

// ---------------- Dense GEMM: Y = h @ W  (100000x64 @ 64x64, bf16 MFMA) -------

__global__ __launch_bounds__(256) void k_gemm(
        const unsigned short* __restrict__ hin, const float* __restrict__ W,
        unsigned short* __restrict__ Y) {
    int lane = threadIdx.x & 63;
    int r = lane & 15;
    int g = lane >> 4;
    int wave   = blockIdx.x * (blockDim.x >> 6) + (threadIdx.x >> 6);
    int nwaves = gridDim.x * (blockDim.x >> 6);

    short8 bh[2][4], bl[2][4];
    #pragma unroll
    for (int s = 0; s < 2; ++s) {
        #pragma unroll
        for (int t = 0; t < 4; ++t) {
            short8 hv, lv;
            #pragma unroll
            for (int i = 0; i < 8; ++i) {
                int k = s * 32 + g * 8 + i;
                int n = t * 16 + r;
                float w = W[k * 64 + n];
                unsigned short wh = f2bf(w);
                float whf = bf2f(wh);
                hv[i] = (short)wh;
                lv[i] = (short)f2bf(w - whf);
            }
            bh[s][t] = hv; bl[s][t] = lv;
        }
    }

    const int NT = N_NODES / 16;   // 6250 (exact)
    for (int mt = wave; mt < NT; mt += nwaves) {
        const unsigned short* arow = hin + (size_t)(mt * 16 + r) * 64;
        short8 a0 = *(const short8*)(arow + g * 8);
        short8 a1 = *(const short8*)(arow + 32 + g * 8);
        #pragma unroll
        for (int t = 0; t < 4; ++t) {
            f32x4 acc = {0.f, 0.f, 0.f, 0.f};
            acc = __builtin_amdgcn_mfma_f32_16x16x32_bf16(a0, bh[0][t], acc, 0, 0, 0);
            acc = __builtin_amdgcn_mfma_f32_16x16x32_bf16(a0, bl[0][t], acc, 0, 0, 0);
            acc = __builtin_amdgcn_mfma_f32_16x16x32_bf16(a1, bh[1][t], acc, 0, 0, 0);
            acc = __builtin_amdgcn_mfma_f32_16x16x32_bf16(a1, bl[1][t], acc, 0, 0, 0);
            #pragma unroll
            for (int j = 0; j < 4; ++j) {
                sth(&Y[(size_t)(mt * 16 + g * 4 + j) * 64 + t * 16 + r], acc[j]);
            }
        }
    }
}

// ---------------- Gather: out = relu(b + (1+eps)*Y_self + sum_nbr Y_nbr) ------
// 16 lanes per node (4 nodes/wave). Lane sl holds feature quad 4sl..4sl+3.
// dd[8] uint2 in flight (proven round-12 shape, VGPR ~28).

__device__ inline void gather_node(
        const uint2* __restrict__ h2, const int* __restrict__ off,
        const int* __restrict__ adj, int node, int sl, int g4,
        float& a0, float& a1, float& a2, float& a3) {
    int o0 = off[node], o1 = off[node + 1];
    int deg = o1 - o0;
    int nchunk = (deg + 15) >> 4;
    for (int c = 0; c < nchunk; ++c) {
        int pos = o0 + (c << 4) + sl;
        int posc = pos < o1 ? pos : (o1 - 1);
        int idxv = adj[posc];
        int rem = deg - (c << 4);
        #pragma unroll
        for (int half = 0; half < 2; ++half) {
            uint2 dd[8];
            #pragma unroll
            for (int i = 0; i < 8; ++i) {
                int k = half * 8 + i;
                int s = __shfl(idxv, (g4 << 4) + k);
                dd[i] = h2[(size_t)s * 16 + sl];
            }
            #pragma unroll
            for (int i = 0; i < 8; ++i) {
                int k = half * 8 + i;
                int ok = k < rem;
                unsigned int lo = ok ? dd[i].x : 0u;
                unsigned int hc = ok ? dd[i].y : 0u;
                a0 += bflo(lo); a1 += bfhi(lo);
                a2 += bflo(hc); a3 += bfhi(hc);
            }
            if (rem <= 8) break;
        }
    }
}

__global__ __launch_bounds__(512) void k_gather(
        const unsigned short* __restrict__ Y, const int* __restrict__ off,
        const int* __restrict__ adj, const float* __restrict__ epsp,
        const float* __restrict__ b, unsigned short* __restrict__ hout) {
    int tid  = blockIdx.x * 512 + threadIdx.x;
    int node = tid >> 4;
    if (node >= N_NODES) return;
    int sl = threadIdx.x & 15;
    int g4 = (threadIdx.x >> 4) & 3;
    const uint2* h2 = (const uint2*)Y;
    float a0 = 0.f, a1 = 0.f, a2 = 0.f, a3 = 0.f;
    gather_node(h2, off, adj, node, sl, g4, a0, a1, a2, a3);
    uint2 ds = h2[(size_t)node * 16 + sl];
    float ep = 1.0f + epsp[0];
    a0 = fmaxf(a0 + ep * bflo(ds.x) + b[4 * sl + 0], 0.f);
    a1 = fmaxf(a1 + ep * bfhi(ds.x) + b[4 * sl + 1], 0.f);
    a2 = fmaxf(a2 + ep * bflo(ds.y) + b[4 * sl + 2], 0.f);
    a3 = fmaxf(a3 + ep * bfhi(ds.y) + b[4 * sl + 3], 0.f);
    uint2 o;
    o.x = (unsigned int)f2bf(a0) | ((unsigned int)f2bf(a1) << 16);
    o.y = (unsigned int)f2bf(a2) | ((unsigned int)f2bf(a3) << 16);
    ((uint2*)hout)[(size_t)node * 16 + sl] = o;
}

__global__ __launch_bounds__(512) void k_gather_pool(
        const unsigned short* __restrict__ Y, const int* __restrict__ off,
        const int* __restrict__ adj, const float* __restrict__ epsp,
        const float* __restrict__ b, const int* __restrict__ batch,
        float* __restrict__ pooled, int* __restrict__ cnt) {
    __shared__ float sacc[8 * 64];
    __shared__ int   scnt[8];
    for (int i = threadIdx.x; i < 8 * 64; i += 512) sacc[i] = 0.f;
    if (threadIdx.x < 8) scnt[threadIdx.x] = 0;
    __syncthreads();

    int tid  = blockIdx.x * 512 + threadIdx.x;
    int node = tid >> 4;
    int sl = threadIdx.x & 15;
    int g4 = (threadIdx.x >> 4) & 3;
    int g0 = clampi(batch[clampi(blockIdx.x * 32, 0, N_NODES - 1)], 0, N_GRAPHS - 1);

    if (node < N_NODES) {
        const uint2* h2 = (const uint2*)Y;
        float a0 = 0.f, a1 = 0.f, a2 = 0.f, a3 = 0.f;
        gather_node(h2, off, adj, node, sl, g4, a0, a1, a2, a3);
        uint2 ds = h2[(size_t)node * 16 + sl];
        float ep = 1.0f + epsp[0];
        a0 = fmaxf(a0 + ep * bflo(ds.x) + b[4 * sl + 0], 0.f);
        a1 = fmaxf(a1 + ep * bfhi(ds.x) + b[4 * sl + 1], 0.f);
        a2 = fmaxf(a2 + ep * bflo(ds.y) + b[4 * sl + 2], 0.f);
        a3 = fmaxf(a3 + ep * bfhi(ds.y) + b[4 * sl + 3], 0.f);
        int g  = clampi(batch[node], 0, N_GRAPHS - 1);
        int og = g - g0;
        if (og >= 0 && og < 8) {
            atomicAdd(&sacc[og * 64 + 4 * sl + 0], a0);
            atomicAdd(&sacc[og * 64 + 4 * sl + 1], a1);
            atomicAdd(&sacc[og * 64 + 4 * sl + 2], a2);
            atomicAdd(&sacc[og * 64 + 4 * sl + 3], a3);
            if (sl == 0) atomicAdd(&scnt[og], 1);
        } else {
            atomicAdd(&pooled[g * 64 + 4 * sl + 0], a0);
            atomicAdd(&pooled[g * 64 + 4 * sl + 1], a1);
            atomicAdd(&pooled[g * 64 + 4 * sl + 2], a2);
            atomicAdd(&pooled[g * 64 + 4 * sl + 3], a3);
            if (sl == 0) atomicAdd(&cnt[g], 1);
        }
    }
    __syncthreads();
    int w = threadIdx.x >> 6;                // waves 0..7 flush slots
    int lane = threadIdx.x & 63;
    if (w < 8) {
        int c = scnt[w];
        if (c > 0) {
            atomicAdd(&pooled[(g0 + w) * 64 + lane], sacc[w * 64 + lane]);
            if (lane == 0) atomicAdd(&cnt[g0 + w], c);
        }
    }
}

// ---------------- Head: mean, 64->10 relu, 10->1 ----------------

__global__ __launch_bounds__(256) void k_head(
        const float* __restrict__ pooled, const int* __restrict__ cnt,
        const float* __restrict__ Wf1, const float* __restrict__ bf1,
        const float* __restrict__ Wf2, const float* __restrict__ bf2,
        float* __restrict__ out) {
    int g = blockIdx.x * blockDim.x + threadIdx.x;
    if (g >= N_GRAPHS) return;
    float inv = 1.0f / fmaxf((float)cnt[g], 1.0f);
    float p[64];
    #pragma unroll
    for (int k = 0; k < 64; ++k) p[k] = pooled[g * 64 + k] * inv;
    float o = bf2[0];
    #pragma unroll
    for (int j = 0; j < 10; ++j) {
        float s = bf1[j];
        #pragma unroll
        for (int k = 0; k < 64; ++k) s += p[k] * Wf1[k * 10 + j];
        o += fmaxf(s, 0.f) * Wf2[j];
    }
    out[g] = o;
}

// ---------------- launch ----------------

extern "C" void kernel_launch(void* const* d_in, const int* in_sizes, int n_in,
                              void* d_out, int out_size, void* d_ws, size_t ws_size,
                              hipStream_t stream) {
    const float* x     = (const float*)d_in[0];
    const int*   ei    = (const int*)d_in[1];    // int64 in ref -> int32 on device
    const int*   batch = (const int*)d_in[2];
    const float* eps1 = (const float*)d_in[3];
    const float* eps2 = (const float*)d_in[4];
    const float* eps3 = (const float*)d_in[5];
    const float* W1 = (const float*)d_in[6];
    const float* b1 = (const float*)d_in[7];
    const float* W2 = (const float*)d_in[8];
    const float* b2 = (const float*)d_in[9];
    const float* W3 = (const float*)d_in[10];
    const float* b3 = (const float*)d_in[11];
    const float* Wf1 = (const float*)d_in[12];
    const float* bf1 = (const float*)d_in[13];
    const float* Wf2 = (const float*)d_in[14];
    const float* bf2 = (const float*)d_in[15];
    float* out = (float*)d_out;

    const size_t H64 = (size_t)N_NODES * HDIM;          // 6,400,000 elems

    char* base = (char*)d_ws;
    unsigned short* hA = (unsigned short*)base;                    // 12.8 MB
    unsigned short* hB = (unsigned short*)(base + H64 * 2);        // 12.8 MB
    unsigned* pairs = (unsigned*)base;   // 12.8 MB, aliases hA (CSR build only)
    char* q = base + 2 * H64 * 2;
    float* pooled = (float*)q;            q += 64000ull * 4;
    int*   cnt    = (int*)q;              q += 1000ull * 4;
    int*   off    = (int*)q;              q += 100004ull * 4;
    int*   btot   = (int*)q;              q += 512ull * 4;
    int*   bbase  = (int*)q;              q += 512ull * 4;
    int*   gcur   = (int*)q;              q += 512ull * 4;
    int*   adj    = (int*)q;

    const int TB = 256;
    k_zero<<<(65000 + TB - 1) / TB, TB, 0, stream>>>((int*)pooled, 65000);
    k_zero<<<2, TB, 0, stream>>>(btot, NBUCK);

    // CSR build: bucket count -> bucket scan -> bin (packed pairs) -> cluster
    const int BINB = (N_EDGES + BIN_CHUNK - 1) / BIN_CHUNK;   // 782
    k_bcount<<<BINB, BIN_T, 0, stream>>>(ei, btot);
    k_bscan<<<1, 512, 0, stream>>>(btot, bbase, gcur, off);
    k_bin<<<BINB, BIN_T, 0, stream>>>(ei, gcur, pairs);
    k_cluster<<<NBUCK, 512, 0, stream>>>(pairs, bbase, off, adj);

    const int L1_BLOCKS = (int)((H64 + TB - 1) / TB);        // 4 nodes/block @256
    const int GB = (N_NODES * 16 + 511) / 512;               // 3125 (32 nodes/blk)

    // layer 1 (fused, cheap gathers of 12B x-rows)
    k_layer1<<<L1_BLOCKS, TB, 0, stream>>>(x, off, adj, eps1, W1, b1, hA);
    // layer 2: GEMM then gather
    k_gemm<<<256, 256, 0, stream>>>(hA, W2, hB);
    k_gather<<<GB, 512, 0, stream>>>(hB, off, adj, eps2, b2, hA);
    // layer 3: GEMM then gather+pool
    k_gemm<<<256, 256, 0, stream>>>(hA, W3, hB);
    k_gather_pool<<<GB, 512, 0, stream>>>(hB, off, adj, eps3, b3, batch, pooled, cnt);

    k_head<<<(N_GRAPHS + TB - 1) / TB, TB, 0, stream>>>(pooled, cnt, Wf1, bf1, Wf2, bf2, out);
}

// Round 15
// 246.495 us; speedup vs baseline: 1.2388x; 1.0812x over previous
//
#include <hip/hip_runtime.h>

#define N_NODES  100000
#define N_EDGES  3200000
#define N_GRAPHS 1000
#define HDIM     64

#define BUCK_LOG 8
#define BUCK_SZ  256
#define NBUCK    ((N_NODES + BUCK_SZ - 1) / BUCK_SZ)   // 391
#define CAP      16384                                 // slack slots per bucket
#define BIN_T    256
#define BIN_E    16
#define BIN_CHUNK (BIN_T * BIN_E)                      // 4096
#define CLUS_CAP 12288                                 // 48KB LDS adj slice

typedef __attribute__((ext_vector_type(8))) short short8;
typedef __attribute__((ext_vector_type(4))) float f32x4;
typedef __attribute__((ext_vector_type(4))) int   int4v;

// ---------------- bf16 (storage) <-> f32 (math) ----------------

__device__ inline unsigned short f2bf(float v) {
    unsigned int b; __builtin_memcpy(&b, &v, 4);
    return (unsigned short)((b + 0x7FFFu + ((b >> 16) & 1u)) >> 16);   // RNE
}
__device__ inline float bf2f(unsigned short u) {
    return __uint_as_float(((unsigned int)u) << 16);
}
__device__ inline void sth(unsigned short* p, float v) { *p = f2bf(v); }
__device__ inline float bflo(unsigned int d) { return __uint_as_float(d << 16); }
__device__ inline float bfhi(unsigned int d) { return __uint_as_float(d & 0xFFFF0000u); }

__device__ inline int clampi(int v, int lo, int hi) {
    return v < lo ? lo : (v > hi ? hi : v);
}

// ---------------- utility ----------------

__global__ void k_zero(int* __restrict__ p, int n) {
    int i = blockIdx.x * blockDim.x + threadIdx.x;
    if (i < n) p[i] = 0;
}

__global__ void k_curinit(int* __restrict__ gcur) {
    int b = blockIdx.x * blockDim.x + threadIdx.x;
    if (b < NBUCK) gcur[b] = b * CAP;
}

// zero the sentinel feature row (index N_NODES) of both h buffers
__global__ void k_zrow(uint2* __restrict__ hA, uint2* __restrict__ hB) {
    int t = threadIdx.x;
    uint2 z; z.x = 0u; z.y = 0u;
    if (t < 16)       hA[(size_t)N_NODES * 16 + t] = z;
    else if (t < 32)  hB[(size_t)N_NODES * 16 + (t - 16)] = z;
}

// ---------------- CSR build: bin (slack buckets) + cluster (padded) ----------

// Pass 1: bin edges by dst bucket; packed 4B pairs ((dlocal<<24)|src).
__global__ __launch_bounds__(BIN_T) void k_bin(
        const int* __restrict__ ei, int* __restrict__ gcur,
        unsigned* __restrict__ pairs) {
    __shared__ int hist[NBUCK];
    __shared__ int base[NBUCK];
    for (int i = threadIdx.x; i < NBUCK; i += BIN_T) hist[i] = 0;
    __syncthreads();
    int e0 = blockIdx.x * BIN_CHUNK + threadIdx.x * BIN_E;
    int d[BIN_E], s[BIN_E];
    if (e0 + BIN_E <= N_EDGES) {
        const int4v* s4 = (const int4v*)ei;
        const int4v* d4 = (const int4v*)(ei + N_EDGES);
        #pragma unroll
        for (int q = 0; q < 4; ++q) {
            int4v dv = d4[(e0 >> 2) + q];
            int4v sv = s4[(e0 >> 2) + q];
            #pragma unroll
            for (int j = 0; j < 4; ++j) {
                d[q * 4 + j] = clampi(dv[j], 0, N_NODES - 1);
                s[q * 4 + j] = clampi(sv[j], 0, N_NODES - 1);
            }
        }
        #pragma unroll
        for (int k = 0; k < BIN_E; ++k) atomicAdd(&hist[d[k] >> BUCK_LOG], 1);
    } else {
        for (int k = 0; k < BIN_E; ++k) {
            int e = e0 + k;
            bool v = e < N_EDGES;
            d[k] = v ? clampi(ei[N_EDGES + e], 0, N_NODES - 1) : -1;
            s[k] = v ? clampi(ei[e], 0, N_NODES - 1) : 0;
            if (v) atomicAdd(&hist[d[k] >> BUCK_LOG], 1);
        }
    }
    __syncthreads();
    for (int i = threadIdx.x; i < NBUCK; i += BIN_T) {
        int c = hist[i];
        base[i] = c ? atomicAdd(&gcur[i], c) : 0;
        hist[i] = 0;                         // reuse as local rank
    }
    __syncthreads();
    #pragma unroll
    for (int k = 0; k < BIN_E; ++k) {
        if (d[k] >= 0) {
            int bk = d[k] >> BUCK_LOG;
            int r = atomicAdd(&hist[bk], 1);
            int idx = base[bk] + r;
            if (idx < (bk + 1) * CAP)
                pairs[idx] = ((unsigned)(d[k] & (BUCK_SZ - 1)) << 24) | (unsigned)s[k];
        }
    }
}

// Pass 2: one block per bucket. Derives padded per-node offsets (pad to 16
// with sentinel N_NODES), writes packed poff = start | (nch<<24), and the
// padded adj slice via LDS scatter + coalesced stream-out.
__global__ __launch_bounds__(512) void k_cluster(
        const unsigned* __restrict__ pairs, const int* __restrict__ gcur,
        int* __restrict__ poff, int* __restrict__ adj) {
    __shared__ int ladj[CLUS_CAP];
    __shared__ int lcur[BUCK_SZ];
    __shared__ int lsc[BUCK_SZ];
    __shared__ int ptot;
    int b  = blockIdx.x;
    int lo = b * BUCK_SZ;
    int nn = N_NODES - lo; if (nn > BUCK_SZ) nn = BUCK_SZ;
    int e0 = b * CAP;
    int cnt = gcur[b] - e0; if (cnt > CAP) cnt = CAP;
    int t = threadIdx.x;
    if (t < BUCK_SZ) lcur[t] = 0;
    __syncthreads();
    for (int i = t; i < cnt; i += 512) atomicAdd(&lcur[pairs[e0 + i] >> 24], 1);
    __syncthreads();
    int deg = 0, pdeg = 0;
    if (t < BUCK_SZ) {
        deg  = lcur[t];
        pdeg = (deg + 15) & ~15;
        if (pdeg > 2032) pdeg = 2032;        // nch fits 7 bits (never expected)
        lsc[t] = pdeg;
    }
    __syncthreads();
    #pragma unroll
    for (int d = 1; d < BUCK_SZ; d <<= 1) {
        int add = 0;
        if (t < BUCK_SZ && t >= d) add = lsc[t - d];
        __syncthreads();
        if (t < BUCK_SZ) lsc[t] += add;
        __syncthreads();
    }
    if (t == BUCK_SZ - 1) ptot = lsc[t];
    if (t < BUCK_SZ) {
        int exc = lsc[t] - pdeg;
        if (t < nn) poff[lo + t] = (e0 + exc) | ((pdeg >> 4) << 24);
        lcur[t] = exc;
    }
    __syncthreads();
    int pt = ptot;
    if (pt <= CLUS_CAP) {
        for (int i = t; i < pt; i += 512) ladj[i] = N_NODES;
        __syncthreads();
        for (int i = t; i < cnt; i += 512) {
            unsigned p = pairs[e0 + i];
            int pos = atomicAdd(&lcur[p >> 24], 1);
            ladj[pos] = (int)(p & 0xFFFFFFu);
        }
        __syncthreads();
        for (int i = t; i < pt; i += 512) adj[e0 + i] = ladj[i];
    } else {                                  // safety fallback (never expected)
        for (int i = t; i < pt && i < CAP + 4096; i += 512) adj[e0 + i] = N_NODES;
        __syncthreads();
        for (int i = t; i < cnt; i += 512) {
            unsigned p = pairs[e0 + i];
            int pos = atomicAdd(&lcur[p >> 24], 1);
            if (pos < CAP + 4096) adj[e0 + pos] = (int)(p & 0xFFFFFFu);
        }
    }
}

// ---------------- Layer 1 (F_IN = 3): fused agg + 3x64 matmul ----------------

__global__ __launch_bounds__(256) void k_layer1(
        const float* __restrict__ x, const int* __restrict__ poff,
        const int* __restrict__ adj, const float* __restrict__ epsp,
        const float* __restrict__ W1, const float* __restrict__ b1,
        unsigned short* __restrict__ hout) {
    int wid  = (blockIdx.x * blockDim.x + threadIdx.x) >> 6;   // node
    int lane = threadIdx.x & 63;
    if (wid >= N_NODES) return;
    int pk = poff[wid];
    int st = pk & 0xFFFFFF;
    int n16 = ((unsigned)pk >> 24) << 4;
    float a0 = 0.f, a1 = 0.f, a2 = 0.f;
    for (int e = lane; e < n16; e += 64) {
        int s = adj[st + e];
        bool ok = s < N_NODES;
        int sc = ok ? s : 0;
        float m = ok ? 1.f : 0.f;
        a0 += m * x[sc * 3 + 0];
        a1 += m * x[sc * 3 + 1];
        a2 += m * x[sc * 3 + 2];
    }
    #pragma unroll
    for (int d = 32; d; d >>= 1) {
        a0 += __shfl_xor(a0, d);
        a1 += __shfl_xor(a1, d);
        a2 += __shfl_xor(a2, d);
    }
    float ep = 1.0f + epsp[0];
    float s0 = ep * x[wid * 3 + 0] + a0;
    float s1 = ep * x[wid * 3 + 1] + a1;
    float s2 = ep * x[wid * 3 + 2] + a2;
    float o = b1[lane] + s0 * W1[lane] + s1 * W1[64 + lane] + s2 * W1[128 + lane];
    sth(&hout[(size_t)wid * 64 + lane], fmaxf(o, 0.f));
}

// ---------------- Dense GEMM: Y = h @ W  (100000x64 @ 64x64, bf16 MFMA) -------

__global__ __launch_bounds__(256) void k_gemm(
        const unsigned short* __restrict__ hin, const float* __restrict__ W,
        unsigned short* __restrict__ Y) {
    int lane = threadIdx.x & 63;
    int r = lane & 15;
    int g = lane >> 4;
    int wave   = blockIdx.x * (blockDim.x >> 6) + (threadIdx.x >> 6);
    int nwaves = gridDim.x * (blockDim.x >> 6);

    short8 bh[2][4], bl[2][4];
    #pragma unroll
    for (int s = 0; s < 2; ++s) {
        #pragma unroll
        for (int t = 0; t < 4; ++t) {
            short8 hv, lv;
            #pragma unroll
            for (int i = 0; i < 8; ++i) {
                int k = s * 32 + g * 8 + i;
                int n = t * 16 + r;
                float w = W[k * 64 + n];
                unsigned short wh = f2bf(w);
                float whf = bf2f(wh);
                hv[i] = (short)wh;
                lv[i] = (short)f2bf(w - whf);
            }
            bh[s][t] = hv; bl[s][t] = lv;
        }
    }

    const int NT = N_NODES / 16;   // 6250 (exact)
    for (int mt = wave; mt < NT; mt += nwaves) {
        const unsigned short* arow = hin + (size_t)(mt * 16 + r) * 64;
        short8 a0 = *(const short8*)(arow + g * 8);
        short8 a1 = *(const short8*)(arow + 32 + g * 8);
        #pragma unroll
        for (int t = 0; t < 4; ++t) {
            f32x4 acc = {0.f, 0.f, 0.f, 0.f};
            acc = __builtin_amdgcn_mfma_f32_16x16x32_bf16(a0, bh[0][t], acc, 0, 0, 0);
            acc = __builtin_amdgcn_mfma_f32_16x16x32_bf16(a0, bl[0][t], acc, 0, 0, 0);
            acc = __builtin_amdgcn_mfma_f32_16x16x32_bf16(a1, bh[1][t], acc, 0, 0, 0);
            acc = __builtin_amdgcn_mfma_f32_16x16x32_bf16(a1, bl[1][t], acc, 0, 0, 0);
            #pragma unroll
            for (int j = 0; j < 4; ++j) {
                sth(&Y[(size_t)(mt * 16 + g * 4 + j) * 64 + t * 16 + r], acc[j]);
            }
        }
    }
}

// ---------------- Gather: out = relu(b + (1+eps)*Y_self + sum_nbr Y_nbr) ------
// 16 lanes per node. Padded, mask-free: adj lists are multiples of 16 with
// sentinel N_NODES pointing at an all-zero row. dd[16] uint2 in flight.

__device__ inline void gather_node(
        const uint2* __restrict__ h2, int st, int nch,
        const int* __restrict__ adj, int sl, int g4,
        float& a0, float& a1, float& a2, float& a3) {
    for (int c = 0; c < nch; ++c) {
        int idxv = adj[st + (c << 4) + sl];
        uint2 dd[16];
        #pragma unroll
        for (int k = 0; k < 16; ++k) {
            int s = __shfl(idxv, (g4 << 4) + k);
            dd[k] = h2[(size_t)s * 16 + sl];
        }
        #pragma unroll
        for (int k = 0; k < 16; ++k) {
            a0 += bflo(dd[k].x); a1 += bfhi(dd[k].x);
            a2 += bflo(dd[k].y); a3 += bfhi(dd[k].y);
        }
    }
}

__global__ __launch_bounds__(512) void k_gather(
        const unsigned short* __restrict__ Y, const int* __restrict__ poff,
        const int* __restrict__ adj, const float* __restrict__ epsp,
        const float* __restrict__ b, unsigned short* __restrict__ hout) {
    int tid  = blockIdx.x * 512 + threadIdx.x;
    int node = tid >> 4;
    if (node >= N_NODES) return;
    int sl = threadIdx.x & 15;
    int g4 = (threadIdx.x >> 4) & 3;
    int pk = poff[node];
    int st = pk & 0xFFFFFF;
    int nch = (unsigned)pk >> 24;
    const uint2* h2 = (const uint2*)Y;
    float a0 = 0.f, a1 = 0.f, a2 = 0.f, a3 = 0.f;
    gather_node(h2, st, nch, adj, sl, g4, a0, a1, a2, a3);
    uint2 ds = h2[(size_t)node * 16 + sl];
    float ep = 1.0f + epsp[0];
    a0 = fmaxf(a0 + ep * bflo(ds.x) + b[4 * sl + 0], 0.f);
    a1 = fmaxf(a1 + ep * bfhi(ds.x) + b[4 * sl + 1], 0.f);
    a2 = fmaxf(a2 + ep * bflo(ds.y) + b[4 * sl + 2], 0.f);
    a3 = fmaxf(a3 + ep * bfhi(ds.y) + b[4 * sl + 3], 0.f);
    uint2 o;
    o.x = (unsigned int)f2bf(a0) | ((unsigned int)f2bf(a1) << 16);
    o.y = (unsigned int)f2bf(a2) | ((unsigned int)f2bf(a3) << 16);
    ((uint2*)hout)[(size_t)node * 16 + sl] = o;
}

__global__ __launch_bounds__(512) void k_gather_pool(
        const unsigned short* __restrict__ Y, const int* __restrict__ poff,
        const int* __restrict__ adj, const float* __restrict__ epsp,
        const float* __restrict__ b, const int* __restrict__ batch,
        float* __restrict__ pooled, int* __restrict__ cnt) {
    __shared__ float sacc[8 * 64];
    __shared__ int   scnt[8];
    for (int i = threadIdx.x; i < 8 * 64; i += 512) sacc[i] = 0.f;
    if (threadIdx.x < 8) scnt[threadIdx.x] = 0;
    __syncthreads();

    int tid  = blockIdx.x * 512 + threadIdx.x;
    int node = tid >> 4;
    int sl = threadIdx.x & 15;
    int g4 = (threadIdx.x >> 4) & 3;
    int g0 = clampi(batch[clampi(blockIdx.x * 32, 0, N_NODES - 1)], 0, N_GRAPHS - 1);

    if (node < N_NODES) {
        int pk = poff[node];
        int st = pk & 0xFFFFFF;
        int nch = (unsigned)pk >> 24;
        const uint2* h2 = (const uint2*)Y;
        float a0 = 0.f, a1 = 0.f, a2 = 0.f, a3 = 0.f;
        gather_node(h2, st, nch, adj, sl, g4, a0, a1, a2, a3);
        uint2 ds = h2[(size_t)node * 16 + sl];
        float ep = 1.0f + epsp[0];
        a0 = fmaxf(a0 + ep * bflo(ds.x) + b[4 * sl + 0], 0.f);
        a1 = fmaxf(a1 + ep * bfhi(ds.x) + b[4 * sl + 1], 0.f);
        a2 = fmaxf(a2 + ep * bflo(ds.y) + b[4 * sl + 2], 0.f);
        a3 = fmaxf(a3 + ep * bfhi(ds.y) + b[4 * sl + 3], 0.f);
        int g  = clampi(batch[node], 0, N_GRAPHS - 1);
        int og = g - g0;
        if (og >= 0 && og < 8) {
            atomicAdd(&sacc[og * 64 + 4 * sl + 0], a0);
            atomicAdd(&sacc[og * 64 + 4 * sl + 1], a1);
            atomicAdd(&sacc[og * 64 + 4 * sl + 2], a2);
            atomicAdd(&sacc[og * 64 + 4 * sl + 3], a3);
            if (sl == 0) atomicAdd(&scnt[og], 1);
        } else {
            atomicAdd(&pooled[g * 64 + 4 * sl + 0], a0);
            atomicAdd(&pooled[g * 64 + 4 * sl + 1], a1);
            atomicAdd(&pooled[g * 64 + 4 * sl + 2], a2);
            atomicAdd(&pooled[g * 64 + 4 * sl + 3], a3);
            if (sl == 0) atomicAdd(&cnt[g], 1);
        }
    }
    __syncthreads();
    int w = threadIdx.x >> 6;                // waves 0..7 flush slots
    int lane = threadIdx.x & 63;
    if (w < 8) {
        int c = scnt[w];
        if (c > 0) {
            atomicAdd(&pooled[(g0 + w) * 64 + lane], sacc[w * 64 + lane]);
            if (lane == 0) atomicAdd(&cnt[g0 + w], c);
        }
    }
}

// ---------------- Head: mean, 64->10 relu, 10->1 ----------------

__global__ __launch_bounds__(256) void k_head(
        const float* __restrict__ pooled, const int* __restrict__ cnt,
        const float* __restrict__ Wf1, const float* __restrict__ bf1,
        const float* __restrict__ Wf2, const float* __restrict__ bf2,
        float* __restrict__ out) {
    int g = blockIdx.x * blockDim.x + threadIdx.x;
    if (g >= N_GRAPHS) return;
    float inv = 1.0f / fmaxf((float)cnt[g], 1.0f);
    float p[64];
    #pragma unroll
    for (int k = 0; k < 64; ++k) p[k] = pooled[g * 64 + k] * inv;
    float o = bf2[0];
    #pragma unroll
    for (int j = 0; j < 10; ++j) {
        float s = bf1[j];
        #pragma unroll
        for (int k = 0; k < 64; ++k) s += p[k] * Wf1[k * 10 + j];
        o += fmaxf(s, 0.f) * Wf2[j];
    }
    out[g] = o;
}

// ---------------- launch ----------------

extern "C" void kernel_launch(void* const* d_in, const int* in_sizes, int n_in,
                              void* d_out, int out_size, void* d_ws, size_t ws_size,
                              hipStream_t stream) {
    const float* x     = (const float*)d_in[0];
    const int*   ei    = (const int*)d_in[1];    // int64 in ref -> int32 on device
    const int*   batch = (const int*)d_in[2];
    const float* eps1 = (const float*)d_in[3];
    const float* eps2 = (const float*)d_in[4];
    const float* eps3 = (const float*)d_in[5];
    const float* W1 = (const float*)d_in[6];
    const float* b1 = (const float*)d_in[7];
    const float* W2 = (const float*)d_in[8];
    const float* b2 = (const float*)d_in[9];
    const float* W3 = (const float*)d_in[10];
    const float* b3 = (const float*)d_in[11];
    const float* Wf1 = (const float*)d_in[12];
    const float* bf1 = (const float*)d_in[13];
    const float* Wf2 = (const float*)d_in[14];
    const float* bf2 = (const float*)d_in[15];
    float* out = (float*)d_out;

    const size_t HROWS = (size_t)(N_NODES + 1) * HDIM;   // +1 sentinel zero row

    char* base = (char*)d_ws;
    unsigned short* hA = (unsigned short*)base;                 // 12.800128 MB
    unsigned short* hB = (unsigned short*)(base + HROWS * 2);   // 12.800128 MB
    unsigned* pairs = (unsigned*)base;   // 25.6256 MB, aliases hA+hB+pooled (build only)
    char* q = base + 2 * HROWS * 2;
    float* pooled = (float*)q;            q += 64000ull * 4;
    int*   cnt    = (int*)q;              q += 1000ull * 4;
    int*   poff   = (int*)q;              q += 100000ull * 4;
    int*   gcur   = (int*)q;              q += 512ull * 4;
    int*   adj    = (int*)q;              // NBUCK*CAP + 4096 ints

    const int TB = 256;
    // CSR build: init cursors -> bin (packed pairs, slack buckets) -> cluster
    k_curinit<<<(NBUCK + TB - 1) / TB, TB, 0, stream>>>(gcur);
    const int BINB = (N_EDGES + BIN_CHUNK - 1) / BIN_CHUNK;   // 782
    k_bin<<<BINB, BIN_T, 0, stream>>>(ei, gcur, pairs);
    k_cluster<<<NBUCK, 512, 0, stream>>>(pairs, gcur, poff, adj);

    // pooled/cnt zero + sentinel rows (after pairs region is dead)
    k_zero<<<(65000 + TB - 1) / TB, TB, 0, stream>>>((int*)pooled, 65000);
    k_zrow<<<1, 64, 0, stream>>>((uint2*)hA, (uint2*)hB);

    const int L1_BLOCKS = (N_NODES * 64 + TB - 1) / TB;      // 4 nodes/block @256
    const int GB = (N_NODES * 16 + 511) / 512;               // 3125 (32 nodes/blk)

    // layer 1 (fused, cheap gathers of 12B x-rows)
    k_layer1<<<L1_BLOCKS, TB, 0, stream>>>(x, poff, adj, eps1, W1, b1, hA);
    // layer 2: GEMM then gather
    k_gemm<<<256, 256, 0, stream>>>(hA, W2, hB);
    k_gather<<<GB, 512, 0, stream>>>(hB, poff, adj, eps2, b2, hA);
    // layer 3: GEMM then gather+pool
    k_gemm<<<256, 256, 0, stream>>>(hA, W3, hB);
    k_gather_pool<<<GB, 512, 0, stream>>>(hB, poff, adj, eps3, b3, batch, pooled, cnt);

    k_head<<<(N_GRAPHS + TB - 1) / TB, TB, 0, stream>>>(pooled, cnt, Wf1, bf1, Wf2, bf2, out);
}